// Round 18
// baseline (157.215 us; speedup 1.0000x reference)
//
#include <hip/hip_runtime.h>

// Round 18: output-d split for true 2 waves/SIMD.
// Block 256 = 4 waves = (g: key-half 2048) x (dh: d-half 128). Each wave: FULL QK
// (duplicated across dh; L1 absorbs dup K reads), PV only for its d-half ->
// O=64 regs, total ~250 -> launch_bounds(256,2), grid 512, 2 blocks/CU.
// Zero main-loop barriers. Base-2 softmax, shuffle-free common path (local max +
// __any trigger), deferred per-lane l partials (cross-lane reduce once at end).
//   d_in: 0=x f32, 1=mask i32, 2=Wk, 3=Wq, 4=Wv
// ws (f16): qT [BT/32][8192] | kT [BT/16][4096] | vT [BT/16][4096]
//   qT: [(qh*8+kc)*512 + l4*128 + tok*8 + j]  (x log2e/16 folded)
//   kT: [kc*512 + ch*128 + key*8 + j]   <-> K[16t+key][kc*32+ch*8+j]
//   vT: [dt*512 + kh*256 + d31*8 + j]   <-> V^T[dt*32+d31][16t+kh*8+j]

typedef __attribute__((ext_vector_type(8)))  _Float16 f16x8;
typedef __attribute__((ext_vector_type(4)))  _Float16 f16x4;
typedef __attribute__((ext_vector_type(4)))  float    f32x4;
typedef __attribute__((ext_vector_type(16))) float    f32x16;

constexpr int Bb = 4;
constexpr int Tt = 4096;
constexpr int Cc = 256;
constexpr int BT = Bb * Tt;

#define MFMA16(a, b, c) __builtin_amdgcn_mfma_f32_16x16x32_f16((a), (b), (c), 0, 0, 0)
#define MFMA32(a, b, c) __builtin_amdgcn_mfma_f32_32x32x16_f16((a), (b), (c), 0, 0, 0)

// ---------------- Kernel A: fused QKV projection (R12 + log2e q-scale) -------
__global__ __launch_bounds__(256) void qkv_proj(
    const float* __restrict__ x,
    const float* __restrict__ Wq, const float* __restrict__ Wk,
    const float* __restrict__ Wv,
    _Float16* __restrict__ qo, _Float16* __restrict__ ko,
    _Float16* __restrict__ vto)
{
    extern __shared__ _Float16 sm[];
    _Float16* xs = sm;              // [128][264]
    _Float16* wsm = sm + 128 * 264; // [128][264]

    const int tid = threadIdx.x;
    const int m0  = blockIdx.x * 128;
    const int ny  = blockIdx.y;
    const int mat = ny >> 1;              // 0=q 1=k 2=v
    const int d0  = (ny & 1) * 128;
    const float* W = (mat == 0) ? Wq : (mat == 1 ? Wk : Wv);

#pragma unroll
    for (int i = 0; i < 32; ++i) {
        int flat = i * 256 + tid;
        int r = flat >> 6, c4 = (flat & 63) << 2;
        float4 v = *reinterpret_cast<const float4*>(x + (size_t)(m0 + r) * Cc + c4);
        f16x4 h = { (_Float16)v.x, (_Float16)v.y, (_Float16)v.z, (_Float16)v.w };
        *reinterpret_cast<f16x4*>(xs + r * 264 + c4) = h;
    }
#pragma unroll
    for (int i = 0; i < 32; ++i) {
        int flat = i * 256 + tid;
        int r = flat >> 6, c4 = (flat & 63) << 2;
        float4 v = *reinterpret_cast<const float4*>(W + (size_t)(d0 + r) * Cc + c4);
        f16x4 h = { (_Float16)v.x, (_Float16)v.y, (_Float16)v.z, (_Float16)v.w };
        *reinterpret_cast<f16x4*>(wsm + r * 264 + c4) = h;
    }
    __syncthreads();

    const int w = tid >> 6, lane = tid & 63;
    const int lr = lane & 15, lg = lane >> 4;

    f32x4 acc[2][8] = {};

#pragma unroll
    for (int kc = 0; kc < 8; ++kc) {
        const int c0 = kc * 32 + lg * 8;
        f16x8 xf[2], wf[8];
#pragma unroll
        for (int mb = 0; mb < 2; ++mb)
            xf[mb] = *reinterpret_cast<const f16x8*>(xs + (w * 32 + mb * 16 + lr) * 264 + c0);
#pragma unroll
        for (int db = 0; db < 8; ++db)
            wf[db] = *reinterpret_cast<const f16x8*>(wsm + (db * 16 + lr) * 264 + c0);
        if (mat != 2) {
#pragma unroll
            for (int mb = 0; mb < 2; ++mb)
#pragma unroll
                for (int db = 0; db < 8; ++db)
                    acc[mb][db] = MFMA16(wf[db], xf[mb], acc[mb][db]);   // D[d][tok]
        } else {
#pragma unroll
            for (int mb = 0; mb < 2; ++mb)
#pragma unroll
                for (int db = 0; db < 8; ++db)
                    acc[mb][db] = MFMA16(xf[mb], wf[db], acc[mb][db]);   // D[tok][d]
        }
    }

    if (mat != 2) {
        // q scale: 1/sqrt(256) * log2(e)  (softmax runs in base-2 domain)
        const float sc = (mat == 0) ? 0.0625f * 1.44269504f : 1.0f;
        const int jj  = (lg & 1) * 4;
#pragma unroll
        for (int mb = 0; mb < 2; ++mb)
#pragma unroll
            for (int db = 0; db < 8; ++db) {
                int m  = m0 + w * 32 + mb * 16 + lr;
                int c  = d0 + db * 16 + lg * 4;
                int kc = c >> 5;
                int ch = (c >> 3) & 3;
                f32x4 a = acc[mb][db];
                f16x4 h = { (_Float16)(a.x * sc), (_Float16)(a.y * sc),
                            (_Float16)(a.z * sc), (_Float16)(a.w * sc) };
                if (mat == 0) {
                    size_t off = (size_t)(m >> 5) * 8192 + (((m >> 4) & 1) * 8 + kc) * 512
                               + ch * 128 + (m & 15) * 8 + jj;
                    *reinterpret_cast<f16x4*>(qo + off) = h;
                } else {
                    size_t off = (size_t)(m >> 4) * 4096 + kc * 512
                               + ch * 128 + (m & 15) * 8 + jj;
                    *reinterpret_cast<f16x4*>(ko + off) = h;
                }
            }
    } else {
        const int jj = (lg & 1) * 4;
        const int kh = (lg >> 1) & 1;
#pragma unroll
        for (int mb = 0; mb < 2; ++mb)
#pragma unroll
            for (int db = 0; db < 8; ++db) {
                int d = d0 + db * 16 + lr;
                int m = m0 + w * 32 + mb * 16 + lg * 4;
                f32x4 a = acc[mb][db];
                f16x4 h = { (_Float16)a.x, (_Float16)a.y, (_Float16)a.z, (_Float16)a.w };
                size_t off = (size_t)(m >> 4) * 4096 + (d >> 5) * 512
                           + kh * 256 + (d & 31) * 8 + jj;
                *reinterpret_cast<f16x4*>(vto + off) = h;
            }
    }
}

// ---------------- Kernel B: d-split register-resident flash attention --------
// LDS (bytes): [0,6144) per-warp P [4][32][24] f16 | [6144,6400) mex f32[2g][32]
//              [6400,6656) lex | [6656,40448) oex f32[2 dh][32 q][132]
__global__ __launch_bounds__(256, 2) void attn_kernel(
    const _Float16* __restrict__ qb, const _Float16* __restrict__ kb,
    const _Float16* __restrict__ vtb, const int* __restrict__ mask,
    float* __restrict__ outp)
{
    extern __shared__ char smraw[];
    float* mex  = (float*)(smraw + 6144);
    float* lex  = (float*)(smraw + 6400);
    float* oexf = (float*)(smraw + 6656);

    const int tid = threadIdx.x, w = tid >> 6, lane = tid & 63;
    const int dh = w & 1, g = w >> 1;
    const int l15 = lane & 15, l4 = lane >> 4;
    const int l31 = lane & 31, l5 = lane >> 5;

    const int bid = blockIdx.x;
    const int b   = (bid & 7) >> 1;                    // batch -> XCD pair
    const int qt  = ((bid >> 3) << 1) | (bid & 1);     // [0,128)
    const int q0  = qt * 32;
    const size_t base = (size_t)b * Tt * Cc;
    const int* maskb = mask + (size_t)b * Tt;
    const _Float16* kTb = kb + base;
    const _Float16* vTb = vtb + base;

    // Q fragments (full 256c): Q[q0 + qh*16 + l15][kc*32 + l4*8 + j] (x log2e/16)
    f16x8 qf[2][8];
    {
        const _Float16* qTb = qb + (size_t)(b * 128 + qt) * 8192;
#pragma unroll
        for (int qh = 0; qh < 2; ++qh)
#pragma unroll
            for (int kc = 0; kc < 8; ++kc)
                qf[qh][kc] = *reinterpret_cast<const f16x8*>(
                    qTb + (qh * 8 + kc) * 512 + l4 * 128 + l15 * 8);
    }

    _Float16* pw = (_Float16*)smraw + w * 768;         // [32][24] private bounce

    f32x16 o[4] = {};        // O^T[d = dh*128 + dt*32+(r&3)+8*(r>>2)+4*l5][q=l31]
    float m0r = -60.f, m1r = -60.f, l0r = 0.f, l1r = 0.f;   // l: per-lane partials

    auto LOADK = [&](f16x8 (&kr)[8], int4& mc, int tile) {
        const _Float16* kp = kTb + (size_t)tile * 4096 + l4 * 128 + l15 * 8;
#pragma unroll
        for (int kc = 0; kc < 8; ++kc)
            kr[kc] = *reinterpret_cast<const f16x8*>(kp + kc * 512);
        mc = *reinterpret_cast<const int4*>(maskb + tile * 16 + l4 * 4);
    };

    f16x8 vr[4];             // single-buffered V half (loaded early in COMPUTE)
    auto COMPUTE = [&](f16x8 (&kr)[8], int4 mc, int tile) {
        // V(tile) for this d-half: arrives during QK+softmax
        {
            const _Float16* vp = vTb + (size_t)tile * 4096 + dh * 2048
                               + l5 * 256 + l31 * 8;
#pragma unroll
            for (int dt = 0; dt < 4; ++dt)
                vr[dt] = *reinterpret_cast<const f16x8*>(vp + dt * 512);
        }

        // QK (full): S^T[key = l4*4 + r][q = qh*16 + l15]
        f32x4 s40 = { 0.f, 0.f, 0.f, 0.f }, s41 = { 0.f, 0.f, 0.f, 0.f };
#pragma unroll
        for (int kc = 0; kc < 8; ++kc) {
            s40 = MFMA16(kr[kc], qf[0][kc], s40);
            s41 = MFMA16(kr[kc], qf[1][kc], s41);
        }
        if (mc.x == 0) { s40[0] = -1e30f; s41[0] = -1e30f; }
        if (mc.y == 0) { s40[1] = -1e30f; s41[1] = -1e30f; }
        if (mc.z == 0) { s40[2] = -1e30f; s41[2] = -1e30f; }
        if (mc.w == 0) { s40[3] = -1e30f; s41[3] = -1e30f; }

        // shuffle-free common path: lane-local max + __any trigger
        float t0l = fmaxf(fmaxf(s40[0], s40[1]), fmaxf(s40[2], s40[3]));
        float t1l = fmaxf(fmaxf(s41[0], s41[1]), fmaxf(s41[2], s41[3]));
        if (__any(t0l > m0r + 11.54f || t1l > m1r + 11.54f)) {   // 2^11.54 ~ e^8
            float t0 = t0l, t1 = t1l;
            t0 = fmaxf(t0, __shfl_xor(t0, 16, 64)); t0 = fmaxf(t0, __shfl_xor(t0, 32, 64));
            t1 = fmaxf(t1, __shfl_xor(t1, 16, 64)); t1 = fmaxf(t1, __shfl_xor(t1, 32, 64));
            float mn0 = fmaxf(m0r, t0), mn1 = fmaxf(m1r, t1);
            float c0 = exp2f(m0r - mn0), c1 = exp2f(m1r - mn1);
            m0r = mn0; m1r = mn1; l0r *= c0; l1r *= c1;
            float cs = (lane & 16) ? c1 : c0;              // o cols: q = l31
#pragma unroll
            for (int dt = 0; dt < 4; ++dt) o[dt] *= cs;
        }

        // exp2 + per-lane l partials (cross-lane reduce deferred to epilogue)
#pragma unroll
        for (int r = 0; r < 4; ++r) {
            float p0 = exp2f(s40[r] - m0r); s40[r] = p0; l0r += p0;
            float p1 = exp2f(s41[r] - m1r); s41[r] = p1; l1r += p1;
        }

        // P -> pw[q][k] f16; reread as PV B-frag (private, in-wave lgkm-ordered)
        {
            f16x4 h0 = { (_Float16)s40[0], (_Float16)s40[1], (_Float16)s40[2], (_Float16)s40[3] };
            f16x4 h1 = { (_Float16)s41[0], (_Float16)s41[1], (_Float16)s41[2], (_Float16)s41[3] };
            *reinterpret_cast<f16x4*>(pw + l15 * 24 + l4 * 4)        = h0;
            *reinterpret_cast<f16x4*>(pw + (16 + l15) * 24 + l4 * 4) = h1;
        }
        f16x8 pf = *reinterpret_cast<const f16x8*>(pw + l31 * 24 + l5 * 8);

        // PV (d-half): O^T += V^T P^T
#pragma unroll
        for (int dt = 0; dt < 4; ++dt)
            o[dt] = MFMA32(vr[dt], pf, o[dt]);
    };

    // main loop: 128 tiles of 16 keys, K ping-pong, NO barriers
    f16x8 kA[8], kB[8];
    int4 mA_, mB_;
    const int ktb = g * 128;                 // this wave's tiles [ktb, ktb+128)
    LOADK(kA, mA_, ktb);
#pragma unroll 1
    for (int t2 = 0; t2 < 64; ++t2) {
        LOADK(kB, mB_, ktb + 2 * t2 + 1);
        COMPUTE(kA, mA_, ktb + 2 * t2);
        LOADK(kA, mA_, (2 * t2 + 2 < 128) ? (ktb + 2 * t2 + 2) : ktb);  // last: dummy
        COMPUTE(kB, mB_, ktb + 2 * t2 + 1);
    }

    // ---- epilogue ----
    // deferred l reduction (per q = l15 / 16+l15)
    float L0 = l0r; L0 += __shfl_xor(L0, 16, 64); L0 += __shfl_xor(L0, 32, 64);
    float L1 = l1r; L1 += __shfl_xor(L1, 16, 64); L1 += __shfl_xor(L1, 32, 64);

    if (dh == 0 && l4 == 0) {           // dh waves hold identical m/l
        mex[g * 32 + l15]      = m0r;  mex[g * 32 + 16 + l15] = m1r;
        lex[g * 32 + l15]      = L0;   lex[g * 32 + 16 + l15] = L1;
    }
    __syncthreads();

    {
        float mst = fmaxf(mex[l31], mex[32 + l31]);
        float mq  = (lane & 16) ? m1r : m0r;
        float osc = exp2f(mq - mst);
        float* oq = oexf + dh * 4224;        // [32 q][132]
        if (g == 1) {
#pragma unroll
            for (int dt = 0; dt < 4; ++dt)
#pragma unroll
                for (int r = 0; r < 16; ++r) {
                    int dloc = dt * 32 + (r & 3) + 8 * (r >> 2) + 4 * l5;
                    oq[l31 * 132 + dloc] = o[dt][r] * osc;
                }
        }
        __syncthreads();
        if (g == 0) {
#pragma unroll
            for (int dt = 0; dt < 4; ++dt)
#pragma unroll
                for (int r = 0; r < 16; ++r) {
                    int dloc = dt * 32 + (r & 3) + 8 * (r >> 2) + 4 * l5;
                    oq[l31 * 132 + dloc] += o[dt][r] * osc;
                }
        }
        __syncthreads();
    }

    // readout: q = tid>>3 in [0,32), seg = tid&7 -> 32 d each
    {
        const int q = tid >> 3, seg = tid & 7;
        const int ds0 = seg * 32, dhr = seg >> 2, dl0 = (seg & 3) * 32;
        float mA2 = mex[q], mB2 = mex[32 + q];
        float ms  = fmaxf(mA2, mB2);
        float lt  = lex[q] * exp2f(mA2 - ms) + lex[32 + q] * exp2f(mB2 - ms);
        float inv = 1.f / lt;
        const float* src = oexf + dhr * 4224 + q * 132 + dl0;
        float* dst = outp + base + (size_t)(q0 + q) * Cc + ds0;
#pragma unroll
        for (int i = 0; i < 8; ++i) {
            f32x4 a = *reinterpret_cast<const f32x4*>(src + 4 * i);
            a[0] *= inv; a[1] *= inv; a[2] *= inv; a[3] *= inv;
            *reinterpret_cast<f32x4*>(dst + 4 * i) = a;
        }
    }
}

extern "C" void kernel_launch(void* const* d_in, const int* in_sizes, int n_in,
                              void* d_out, int out_size, void* d_ws, size_t ws_size,
                              hipStream_t stream)
{
    (void)in_sizes; (void)n_in; (void)out_size; (void)ws_size;
    const float* x   = (const float*)d_in[0];
    const int*  mask = (const int*)d_in[1];
    const float* Wk  = (const float*)d_in[2];
    const float* Wq  = (const float*)d_in[3];
    const float* Wv  = (const float*)d_in[4];
    float* out = (float*)d_out;

    _Float16* q  = (_Float16*)d_ws;
    _Float16* k  = q + (size_t)BT * Cc;
    _Float16* vt = k + (size_t)BT * Cc;

    dim3 gA(128, 6), blkA(256);
    size_t ldsA = (size_t)(128 + 128) * 264 * sizeof(_Float16);
    qkv_proj<<<gA, blkA, ldsA, stream>>>(x, Wq, Wk, Wv, q, k, vt);

    dim3 gB(512), blkB(256);
    size_t ldsB = 40448;
    attn_kernel<<<gB, blkB, ldsB, stream>>>(q, k, vt, mask, out);
}

// Round 20
// 141.722 us; speedup vs baseline: 1.1093x; 1.1093x over previous
//
#include <hip/hip_runtime.h>

// Round 20: R19 with builtin-name fix (__builtin_amdgcn_mfma_f32_16x16x16f16).
// ZERO-LDS main loop: swapped-QK S^T[key=l4*4+r][q=l15] IS the A-operand layout
// of mfma 16x16x16 (row=q=lane&15, k=key=(lane>>4)*4+i). PV consumes P straight
// from registers — no LDS bounce, no cross-lane ops. V stored as 16x16x16
// B-frags. Lane-partial l, local-max __any defer path, base-2 softmax.
// Block 256 = 4 waves (1/SIMD) = 2 qw(32q) x 2 g(2048 keys); grid 256; no barriers.
//   d_in: 0=x f32, 1=mask i32, 2=Wk, 3=Wq, 4=Wv
// ws (f16): qT [BT/32][8192] | kT [BT/16][4096] | vT [BT/16][4096]
//   qT: [(qh*8+kc)*512 + l4*128 + tok*8 + j]  (x log2e/16 folded)
//   kT: [kc*512 + ch*128 + key*8 + j]      <-> K[16t+key][kc*32+ch*8+j]
//   vT: [dt*256 + kq*64 + d16*4 + j]       <-> V^T[dt*16+d16][16t+kq*4+j]

typedef __attribute__((ext_vector_type(8)))  _Float16 f16x8;
typedef __attribute__((ext_vector_type(4)))  _Float16 f16x4;
typedef __attribute__((ext_vector_type(4)))  float    f32x4;

constexpr int Bb = 4;
constexpr int Tt = 4096;
constexpr int Cc = 256;
constexpr int BT = Bb * Tt;

#define MFMA16(a, b, c)   __builtin_amdgcn_mfma_f32_16x16x32_f16((a), (b), (c), 0, 0, 0)
#define MFMA1616(a, b, c) __builtin_amdgcn_mfma_f32_16x16x16f16((a), (b), (c), 0, 0, 0)

// ---------------- Kernel A: fused QKV projection ----------------
__global__ __launch_bounds__(256) void qkv_proj(
    const float* __restrict__ x,
    const float* __restrict__ Wq, const float* __restrict__ Wk,
    const float* __restrict__ Wv,
    _Float16* __restrict__ qo, _Float16* __restrict__ ko,
    _Float16* __restrict__ vto)
{
    extern __shared__ _Float16 sm[];
    _Float16* xs = sm;              // [128][264]
    _Float16* wsm = sm + 128 * 264; // [128][264]

    const int tid = threadIdx.x;
    const int m0  = blockIdx.x * 128;
    const int ny  = blockIdx.y;
    const int mat = ny >> 1;              // 0=q 1=k 2=v
    const int d0  = (ny & 1) * 128;
    const float* W = (mat == 0) ? Wq : (mat == 1 ? Wk : Wv);

#pragma unroll
    for (int i = 0; i < 32; ++i) {
        int flat = i * 256 + tid;
        int r = flat >> 6, c4 = (flat & 63) << 2;
        float4 v = *reinterpret_cast<const float4*>(x + (size_t)(m0 + r) * Cc + c4);
        f16x4 h = { (_Float16)v.x, (_Float16)v.y, (_Float16)v.z, (_Float16)v.w };
        *reinterpret_cast<f16x4*>(xs + r * 264 + c4) = h;
    }
#pragma unroll
    for (int i = 0; i < 32; ++i) {
        int flat = i * 256 + tid;
        int r = flat >> 6, c4 = (flat & 63) << 2;
        float4 v = *reinterpret_cast<const float4*>(W + (size_t)(d0 + r) * Cc + c4);
        f16x4 h = { (_Float16)v.x, (_Float16)v.y, (_Float16)v.z, (_Float16)v.w };
        *reinterpret_cast<f16x4*>(wsm + r * 264 + c4) = h;
    }
    __syncthreads();

    const int w = tid >> 6, lane = tid & 63;
    const int lr = lane & 15, lg = lane >> 4;

    f32x4 acc[2][8] = {};

#pragma unroll
    for (int kc = 0; kc < 8; ++kc) {
        const int c0 = kc * 32 + lg * 8;
        f16x8 xf[2], wf[8];
#pragma unroll
        for (int mb = 0; mb < 2; ++mb)
            xf[mb] = *reinterpret_cast<const f16x8*>(xs + (w * 32 + mb * 16 + lr) * 264 + c0);
#pragma unroll
        for (int db = 0; db < 8; ++db)
            wf[db] = *reinterpret_cast<const f16x8*>(wsm + (db * 16 + lr) * 264 + c0);
        if (mat != 2) {
#pragma unroll
            for (int mb = 0; mb < 2; ++mb)
#pragma unroll
                for (int db = 0; db < 8; ++db)
                    acc[mb][db] = MFMA16(wf[db], xf[mb], acc[mb][db]);   // D[d][tok]
        } else {
#pragma unroll
            for (int mb = 0; mb < 2; ++mb)
#pragma unroll
                for (int db = 0; db < 8; ++db)
                    acc[mb][db] = MFMA16(xf[mb], wf[db], acc[mb][db]);   // D[tok][d]
        }
    }

    if (mat != 2) {
        // q scale: 1/sqrt(256) * log2(e)  (softmax runs base-2)
        const float sc = (mat == 0) ? 0.0625f * 1.44269504f : 1.0f;
        const int jj  = (lg & 1) * 4;
#pragma unroll
        for (int mb = 0; mb < 2; ++mb)
#pragma unroll
            for (int db = 0; db < 8; ++db) {
                int m  = m0 + w * 32 + mb * 16 + lr;
                int c  = d0 + db * 16 + lg * 4;
                int kc = c >> 5;
                int ch = (c >> 3) & 3;
                f32x4 a = acc[mb][db];
                f16x4 h = { (_Float16)(a.x * sc), (_Float16)(a.y * sc),
                            (_Float16)(a.z * sc), (_Float16)(a.w * sc) };
                if (mat == 0) {
                    size_t off = (size_t)(m >> 5) * 8192 + (((m >> 4) & 1) * 8 + kc) * 512
                               + ch * 128 + (m & 15) * 8 + jj;
                    *reinterpret_cast<f16x4*>(qo + off) = h;
                } else {
                    size_t off = (size_t)(m >> 4) * 4096 + kc * 512
                               + ch * 128 + (m & 15) * 8 + jj;
                    *reinterpret_cast<f16x4*>(ko + off) = h;
                }
            }
    } else {
        // vT B-frag tile: [dt(16)][kq(4)][d16(16)][j(4)]
        // lane: d = d0+db*16+lr, keys m..m+3 (m&15 = lg*4) -> kq = lg, j run
#pragma unroll
        for (int mb = 0; mb < 2; ++mb)
#pragma unroll
            for (int db = 0; db < 8; ++db) {
                int d = d0 + db * 16 + lr;
                int m = m0 + w * 32 + mb * 16 + lg * 4;
                f32x4 a = acc[mb][db];
                f16x4 h = { (_Float16)a.x, (_Float16)a.y, (_Float16)a.z, (_Float16)a.w };
                size_t off = (size_t)(m >> 4) * 4096 + (size_t)(d >> 4) * 256
                           + lg * 64 + (d & 15) * 4;
                *reinterpret_cast<f16x4*>(vto + off) = h;
            }
    }
}

// ---------------- Kernel B: zero-LDS-loop flash attention ----------------
// LDS (bytes): [0,512) mex f32[4][32] | [512,1024) lex | [1024,67072) oex f32[2][32][258]
__global__ __launch_bounds__(256, 1) void attn_kernel(
    const _Float16* __restrict__ qb, const _Float16* __restrict__ kb,
    const _Float16* __restrict__ vtb, const int* __restrict__ mask,
    float* __restrict__ outp)
{
    extern __shared__ char smraw[];
    float* mex  = (float*)(smraw);
    float* lex  = (float*)(smraw + 512);
    float* oexf = (float*)(smraw + 1024);

    const int tid = threadIdx.x, w = tid >> 6, lane = tid & 63;
    const int qw = w >> 1, g = w & 1;
    const int l15 = lane & 15, l4 = lane >> 4;

    const int bid = blockIdx.x;
    const int b   = (bid & 7) >> 1;                    // batch -> XCD pair
    const int qt  = ((bid >> 3) << 1) | (bid & 1);     // [0,64)
    const int q0  = qt * 64;
    const size_t base = (size_t)b * Tt * Cc;
    const int* maskb = mask + (size_t)b * Tt;
    const _Float16* kTb = kb + base;
    const _Float16* vTb = vtb + base;

    // Q fragments: Q[q0 + qw*32 + qh*16 + l15][kc*32 + l4*8 + j]  (x log2e/16)
    f16x8 qf[2][8];
    {
        const _Float16* qTb = qb + (size_t)(b * 128 + qt * 2 + qw) * 8192;
#pragma unroll
        for (int qh = 0; qh < 2; ++qh)
#pragma unroll
            for (int kc = 0; kc < 8; ++kc)
                qf[qh][kc] = *reinterpret_cast<const f16x8*>(
                    qTb + (qh * 8 + kc) * 512 + l4 * 128 + l15 * 8);
    }

    // O[qh][dt]: D of 16x16x16 -> O[q = qh*16 + l4*4 + r][d = dt*16 + l15]
    f32x4 o[2][16] = {};
    float m0r = -60.f, m1r = -60.f, l0r = 0.f, l1r = 0.f;  // l: per-lane partials

    auto LOADT = [&](f16x8 (&kr)[8], f16x4 (&vr)[16], int4& mc, int tile) {
        const _Float16* kp = kTb + (size_t)tile * 4096 + l4 * 128 + l15 * 8;
#pragma unroll
        for (int kc = 0; kc < 8; ++kc)
            kr[kc] = *reinterpret_cast<const f16x8*>(kp + kc * 512);
        const _Float16* vp = vTb + (size_t)tile * 4096 + l4 * 64 + l15 * 4;
#pragma unroll
        for (int dt = 0; dt < 16; ++dt)
            vr[dt] = *reinterpret_cast<const f16x4*>(vp + dt * 256);
        mc = *reinterpret_cast<const int4*>(maskb + tile * 16 + l4 * 4);
    };

    auto COMPUTE = [&](f16x8 (&kr)[8], f16x4 (&vr)[16], int4 mc) {
        // QK: S^T[key = l4*4 + r][q = qh*16 + l15]; split 4-deep chains
        f32x4 a0 = { 0.f, 0.f, 0.f, 0.f }, b0 = { 0.f, 0.f, 0.f, 0.f };
        f32x4 a1 = { 0.f, 0.f, 0.f, 0.f }, b1 = { 0.f, 0.f, 0.f, 0.f };
#pragma unroll
        for (int kc = 0; kc < 4; ++kc) {
            a0 = MFMA16(kr[kc], qf[0][kc], a0);
            a1 = MFMA16(kr[kc], qf[1][kc], a1);
        }
#pragma unroll
        for (int kc = 4; kc < 8; ++kc) {
            b0 = MFMA16(kr[kc], qf[0][kc], b0);
            b1 = MFMA16(kr[kc], qf[1][kc], b1);
        }
        f32x4 s40 = a0 + b0, s41 = a1 + b1;

        if (mc.x == 0) { s40[0] = -1e30f; s41[0] = -1e30f; }
        if (mc.y == 0) { s40[1] = -1e30f; s41[1] = -1e30f; }
        if (mc.z == 0) { s40[2] = -1e30f; s41[2] = -1e30f; }
        if (mc.w == 0) { s40[3] = -1e30f; s41[3] = -1e30f; }

        // shuffle-free common path: lane-local max + __any trigger (2^11.54~e^8)
        float t0l = fmaxf(fmaxf(s40[0], s40[1]), fmaxf(s40[2], s40[3]));
        float t1l = fmaxf(fmaxf(s41[0], s41[1]), fmaxf(s41[2], s41[3]));
        if (__any(t0l > m0r + 11.54f || t1l > m1r + 11.54f)) {
            float t0 = t0l, t1 = t1l;
            t0 = fmaxf(t0, __shfl_xor(t0, 16, 64)); t0 = fmaxf(t0, __shfl_xor(t0, 32, 64));
            t1 = fmaxf(t1, __shfl_xor(t1, 16, 64)); t1 = fmaxf(t1, __shfl_xor(t1, 32, 64));
            float mn0 = fmaxf(m0r, t0), mn1 = fmaxf(m1r, t1);
            float c0 = exp2f(m0r - mn0), c1 = exp2f(m1r - mn1);
            m0r = mn0; m1r = mn1; l0r *= c0; l1r *= c1;
            // O's q lives at l4*4+r -> fetch per-q corr from lane (l4*4+r)
            f32x4 cv0, cv1;
#pragma unroll
            for (int r = 0; r < 4; ++r) {
                cv0[r] = __shfl(c0, l4 * 4 + r, 64);
                cv1[r] = __shfl(c1, l4 * 4 + r, 64);
            }
#pragma unroll
            for (int dt = 0; dt < 16; ++dt) { o[0][dt] *= cv0; o[1][dt] *= cv1; }
        }

        // exp2 + per-lane l partials (cross-lane reduce deferred to epilogue)
#pragma unroll
        for (int r = 0; r < 4; ++r) {
            float p0 = exp2f(s40[r] - m0r); s40[r] = p0; l0r += p0;
            float p1 = exp2f(s41[r] - m1r); s41[r] = p1; l1r += p1;
        }

        // P directly as 16x16x16 A-frag (row=q=l15, k=key=l4*4+i) — NO LDS
        f16x4 pa0 = { (_Float16)s40[0], (_Float16)s40[1], (_Float16)s40[2], (_Float16)s40[3] };
        f16x4 pa1 = { (_Float16)s41[0], (_Float16)s41[1], (_Float16)s41[2], (_Float16)s41[3] };

        // PV: O[q][d] += P x V   (16x16x16; independent accumulators)
#pragma unroll
        for (int dt = 0; dt < 16; ++dt) {
            o[0][dt] = MFMA1616(pa0, vr[dt], o[0][dt]);
            o[1][dt] = MFMA1616(pa1, vr[dt], o[1][dt]);
        }
    };

    // main loop: 128 tiles of 16 keys, register ping-pong, NO barriers, NO LDS
    f16x8 kA[8], kB[8];
    f16x4 vA[16], vB[16];
    int4 mA_, mB_;
    const int ktb = g * 128;                 // this wave's tiles [ktb, ktb+128)
    LOADT(kA, vA, mA_, ktb);
#pragma unroll 1
    for (int t2 = 0; t2 < 64; ++t2) {
        LOADT(kB, vB, mB_, ktb + 2 * t2 + 1);
        COMPUTE(kA, vA, mA_);
        LOADT(kA, vA, mA_, (2 * t2 + 2 < 128) ? (ktb + 2 * t2 + 2) : ktb);  // last: dummy
        COMPUTE(kB, vB, mB_);
    }

    // ---- epilogue ----
    // deferred l reduction (partials live in the 4 lanes sharing l15)
    float L0 = l0r; L0 += __shfl_xor(L0, 16, 64); L0 += __shfl_xor(L0, 32, 64);
    float L1 = l1r; L1 += __shfl_xor(L1, 16, 64); L1 += __shfl_xor(L1, 32, 64);

    __syncthreads();
    if (lane < 16) {
        mex[w * 32 + lane]      = m0r;  mex[w * 32 + 16 + lane] = m1r;
        lex[w * 32 + lane]      = L0;   lex[w * 32 + 16 + lane] = L1;
    }
    __syncthreads();

    // 2-way split-K merge (g pair), O layout q = qh*16 + l4*4 + r, d = dt*16 + l15
    {
        float* oq = oexf + qw * (32 * 258);
        f32x4 osc[2];
#pragma unroll
        for (int qh = 0; qh < 2; ++qh)
#pragma unroll
            for (int r = 0; r < 4; ++r) {
                int qq = qh * 16 + l4 * 4 + r;
                float mO = mex[(qw * 2 + g) * 32 + qq];
                float mX = mex[(qw * 2 + (1 - g)) * 32 + qq];
                osc[qh][r] = exp2f(mO - fmaxf(mO, mX));
            }
        if (g == 1) {
#pragma unroll
            for (int qh = 0; qh < 2; ++qh)
#pragma unroll
                for (int dt = 0; dt < 16; ++dt)
#pragma unroll
                    for (int r = 0; r < 4; ++r)
                        oq[(qh * 16 + l4 * 4 + r) * 258 + dt * 16 + l15]
                            = o[qh][dt][r] * osc[qh][r];
        }
        __syncthreads();
        if (g == 0) {
#pragma unroll
            for (int qh = 0; qh < 2; ++qh)
#pragma unroll
                for (int dt = 0; dt < 16; ++dt)
#pragma unroll
                    for (int r = 0; r < 4; ++r)
                        oq[(qh * 16 + l4 * 4 + r) * 258 + dt * 16 + l15]
                            += o[qh][dt][r] * osc[qh][r];
        }
        __syncthreads();
    }

    // readout: q = tid>>2 in [0,64), dseg = (tid&3)*64
    {
        const int q = tid >> 2, ds0 = (tid & 3) * 64;
        const int qws = q >> 5, ql = q & 31;
        float mA2 = mex[(qws * 2 + 0) * 32 + ql];
        float mB2 = mex[(qws * 2 + 1) * 32 + ql];
        float ms  = fmaxf(mA2, mB2);
        float lt  = lex[(qws * 2 + 0) * 32 + ql] * exp2f(mA2 - ms)
                  + lex[(qws * 2 + 1) * 32 + ql] * exp2f(mB2 - ms);
        float inv = 1.f / lt;
        const float* src = oexf + qws * (32 * 258) + ql * 258 + ds0;
        float* dst = outp + base + (size_t)(q0 + q) * Cc + ds0;
#pragma unroll
        for (int i = 0; i < 16; ++i) {
            f32x4 a = *reinterpret_cast<const f32x4*>(src + 4 * i);
            a[0] *= inv; a[1] *= inv; a[2] *= inv; a[3] *= inv;
            *reinterpret_cast<f32x4*>(dst + 4 * i) = a;
        }
    }
}

extern "C" void kernel_launch(void* const* d_in, const int* in_sizes, int n_in,
                              void* d_out, int out_size, void* d_ws, size_t ws_size,
                              hipStream_t stream)
{
    (void)in_sizes; (void)n_in; (void)out_size; (void)ws_size;
    const float* x   = (const float*)d_in[0];
    const int*  mask = (const int*)d_in[1];
    const float* Wk  = (const float*)d_in[2];
    const float* Wq  = (const float*)d_in[3];
    const float* Wv  = (const float*)d_in[4];
    float* out = (float*)d_out;

    _Float16* q  = (_Float16*)d_ws;
    _Float16* k  = q + (size_t)BT * Cc;
    _Float16* vt = k + (size_t)BT * Cc;

    dim3 gA(128, 6), blkA(256);
    size_t ldsA = (size_t)(128 + 128) * 264 * sizeof(_Float16);
    qkv_proj<<<gA, blkA, ldsA, stream>>>(x, Wq, Wk, Wv, q, k, vt);

    dim3 gB(256), blkB(256);
    size_t ldsB = 67072;
    attn_kernel<<<gB, blkB, ldsB, stream>>>(q, k, vt, mask, out);
}